// Round 1
// baseline (240.032 us; speedup 1.0000x reference)
//
#include <hip/hip_runtime.h>
#include <math.h>

// (B,S,D,C) = (64, 576, 768, 200)
#define Bsz  64
#define Ssz  576
#define Dsz  768
#define Csz  200
#define NPAD 208        // 13 tiles of 16: 0..199 classes, row 200 = ones (rowsum), 201..207 zero
#define MT   48         // rows per block; grid 768 = exactly 3 blocks/CU serially
#define NKT  12         // K tiles of 64 floats
#define NCH  48         // 16B chunks per W row (768 B)

typedef float f32x4 __attribute__((ext_vector_type(4)));

#define AS_GLOBAL __attribute__((address_space(1)))
#define AS_LDS    __attribute__((address_space(3)))

// async 16B-per-lane global -> LDS (dest = wave-uniform base + lane*16)
__device__ inline void gload16(const void* g, void* l) {
    __builtin_amdgcn_global_load_lds((const AS_GLOBAL unsigned int*)g,
                                     (AS_LDS unsigned int*)l, 16, 0, 0);
}

// one-time: W (200x768 fp32) -> fp8 e4m3 (208x768); row 200 = 1.0 (rowsum), 201..207 = 0
__global__ __launch_bounds__(256) void prep_w8(const float* __restrict__ W,
                                               unsigned int* __restrict__ Wq) {
    const int i   = blockIdx.x * 256 + threadIdx.x;   // u32 index over NPAD*768/4 = 39936
    const int row = i / 192;
    const int col = (i % 192) * 4;
    unsigned int w = 0;
    if (row < Csz) {
        const float4 v = *(const float4*)(W + (size_t)row * Dsz + col);
        w = __builtin_amdgcn_cvt_pk_fp8_f32(v.x, v.y, 0u, false);
        w = __builtin_amdgcn_cvt_pk_fp8_f32(v.z, v.w, w, true);
    } else if (row == Csz) {
        w = 0x38383838u;   // fp8 e4m3 1.0 x4
    }
    Wq[i] = w;
}

// global classifier runs FIRST: out[b,c] = ct[b]·gw[c] + gb[c]  (exact fp32)
__global__ __launch_bounds__(256) void gc_kernel(
    const float* __restrict__ ct, const float* __restrict__ gw,
    const float* __restrict__ gb, float* __restrict__ out) {
    const int b    = blockIdx.x;
    const int wv   = threadIdx.x >> 6;
    const int lane = threadIdx.x & 63;
    const int c    = blockIdx.y * 4 + wv;
    const float* wr = gw + (size_t)c * Dsz + lane * 12;
    const float* cr = ct + (size_t)b * Dsz + lane * 12;
    float s = 0.f;
#pragma unroll
    for (int j = 0; j < 3; ++j) {
        const float4 w = *(const float4*)(wr + 4 * j);
        const float4 x = *(const float4*)(cr + 4 * j);
        s += w.x * x.x + w.y * x.y + w.z * x.z + w.w * x.w;
    }
#pragma unroll
    for (int off = 32; off > 0; off >>= 1) s += __shfl_down(s, off, 64);
    if (lane == 0) out[b * Csz + c] = s + gb[c];
}

// Restructured: X direct global->VGPR (depth-4 pipeline), full W resident in LDS
// (staged once, chunk-column-major = bank-conflict-free reads), ONE barrier total.
// 3 waves x 16 rows = MT=48; grid 768; 1 block/CU (156 KB LDS).
__global__ __launch_bounds__(192, 1) void attn_kernel(
    const float* __restrict__ X,            // (B*S, D) fp32
    const unsigned char* __restrict__ Wq,   // (NPAD, D) fp8 e4m3
    const float* __restrict__ attn_b,       // (C,)
    const float* __restrict__ lam,          // (1,)
    float* __restrict__ out)                // (B, C): gscore already written
{
    // W chunk-column-major: 16B chunk (row r, col c) at slot c*NPAD + r.
    // B-frag read banks: (4m + 2(q&1)) % 32 -> uniform 4 touches/bank (optimal).
    __shared__ unsigned char sW[NPAD * NCH * 16];   // 159744 B

    const int tid  = threadIdx.x;
    const int lane = tid & 63;
    const int w    = tid >> 6;      // 0..2
    const int m    = lane & 15;
    const int q    = lane >> 4;
    const int rowbase = blockIdx.x * MT;
    const int bidx    = blockIdx.x / 12;          // 12 blocks per batch, never crosses

    // ---- X: per-lane pointer lands directly in A-fragment layout.
    // lane (q,m) of wave w owns row w*16+m, k-floats kt*64 + k2*32 + q*8 .. +8
    const float* xp = X + (size_t)(rowbase + w * 16 + m) * Dsz + q * 8;

    // depth-4 prefetch: slot kt&3, pieces j: (j>>1)=k2, (j&1)=lo/hi float4
    f32x4 xa[4][4];
#pragma unroll
    for (int kt = 0; kt < 4; ++kt) {
#pragma unroll
        for (int j = 0; j < 4; ++j)
            xa[kt][j] = *(const f32x4*)(xp + kt * 64 + (j >> 1) * 32 + (j & 1) * 4);
    }

    // ---- stage full W once: 9984 chunks = 156 wave-groups of 64; 52 per wave.
    // slot s = c*NPAD + r  ->  src chunk (r, c); dest linear (gload_lds rule).
#pragma unroll 4
    for (int j = 0; j < 52; ++j) {
        const int g = w * 52 + j;
        const int s = g * 64 + lane;
        const int c = s / NPAD;                    // 16B col 0..47
        const int r = s - c * NPAD;                // row 0..207
        gload16(Wq + (size_t)r * Dsz + c * 16, &sW[(size_t)(g * 64) * 16]);
    }

    f32x4 acc[13];
#pragma unroll
    for (int t = 0; t < 13; ++t) acc[t] = (f32x4){0.f, 0.f, 0.f, 0.f};

    // per-lane W base: chunk c = kt*4 + k2*2 + (q>>1); addr = c*3328 + (t*16+m)*16 + (q&1)*8
    const int wbase = m * 16 + (q & 1) * 8 + (q >> 1) * 3328;

    __syncthreads();   // the ONLY barrier: W resident; X loads 0..3 drained too

#pragma unroll
    for (int kt = 0; kt < NKT; ++kt) {
        const int slot = kt & 3;
#pragma unroll
        for (int k2 = 0; k2 < 2; ++k2) {
            const f32x4 alo = xa[slot][k2 * 2];
            const f32x4 ahi = xa[slot][k2 * 2 + 1];
            union { long l; unsigned int u[2]; } A;
            A.u[0] = __builtin_amdgcn_cvt_pk_fp8_f32(alo.x, alo.y, 0u, false);
            A.u[0] = __builtin_amdgcn_cvt_pk_fp8_f32(alo.z, alo.w, A.u[0], true);
            A.u[1] = __builtin_amdgcn_cvt_pk_fp8_f32(ahi.x, ahi.y, 0u, false);
            A.u[1] = __builtin_amdgcn_cvt_pk_fp8_f32(ahi.z, ahi.w, A.u[1], true);
            const unsigned char* wb = &sW[(kt * 4 + k2 * 2) * 3328 + wbase];
#pragma unroll
            for (int t = 0; t < 13; ++t) {
                const long Bf = *(const long*)(wb + t * 256);
                acc[t] = __builtin_amdgcn_mfma_f32_16x16x32_fp8_fp8(A.l, Bf, acc[t], 0, 0, 0);
            }
        }
        if (kt + 4 < NKT) {   // refill consumed slot with tile kt+4
#pragma unroll
            for (int j = 0; j < 4; ++j)
                xa[slot][j] = *(const f32x4*)(xp + (kt + 4) * 64 + (j >> 1) * 32 + (j & 1) * 4);
        }
    }

    // rowsum via ones-column: tile 12, col 200 => m==8 lanes; row = q*4+r
    float rsv[4];
#pragma unroll
    for (int r = 0; r < 4; ++r) rsv[r] = __shfl(acc[12][r], (lane & 48) + 8, 64);

    const float scale = lam[0] * (1.f / ((float)Ssz * (float)Dsz));
    // epilogue: C/D col = lane&15, row = q*4+reg; reduce tile's 16 rows, atomic add
#pragma unroll
    for (int t = 0; t < 13; ++t) {
        const int c = t * 16 + m;
        if (c < Csz) {
            const float bias = attn_b[c];
            float s = 0.f;
#pragma unroll
            for (int r = 0; r < 4; ++r)
                s += rsv[r] / (1.f + __expf(-(acc[t][r] + bias)));
            s += __shfl_xor(s, 16, 64);
            s += __shfl_xor(s, 32, 64);
            if (q == 0) atomicAdd(&out[bidx * Csz + c], s * scale);
        }
    }
}

extern "C" void kernel_launch(void* const* d_in, const int* in_sizes, int n_in,
                              void* d_out, int out_size, void* d_ws, size_t ws_size,
                              hipStream_t stream) {
    const float* X   = (const float*)d_in[0];
    const float* ct  = (const float*)d_in[1];
    const float* aw  = (const float*)d_in[2];
    const float* ab  = (const float*)d_in[3];
    const float* gw  = (const float*)d_in[4];
    const float* gb  = (const float*)d_in[5];
    const float* lam = (const float*)d_in[6];
    float* out = (float*)d_out;
    unsigned char* Wq = (unsigned char*)d_ws;   // 208*768 = 156 KB fp8

    prep_w8<<<(NPAD * Dsz / 4) / 256, 256, 0, stream>>>(aw, (unsigned int*)Wq);
    gc_kernel<<<dim3(Bsz, Csz / 4), 256, 0, stream>>>(ct, gw, gb, out);
    attn_kernel<<<(Bsz * Ssz) / MT, 192, 0, stream>>>(X, Wq, ab, lam, out);
}

// Round 2
// 205.841 us; speedup vs baseline: 1.1661x; 1.1661x over previous
//
#include <hip/hip_runtime.h>
#include <math.h>

// (B,S,D,C) = (64, 576, 768, 200)
#define Bsz  64
#define Ssz  576
#define Dsz  768
#define Csz  200
#define MT   48         // rows per block; grid 768 = exactly 3 blocks/CU, all co-resident
#define NKT  12         // K tiles of 64 floats

typedef float f32x4 __attribute__((ext_vector_type(4)));
typedef long  lx2   __attribute__((ext_vector_type(2)));

// one-time: W (200x768 fp32) -> fp8 e4m3 pre-swizzled into MFMA B-fragment order.
// Record (kt,t) = 1024 B at ((kt*13+t)*1024): lane l holds 16 B = [k2=0 8B][k2=1 8B],
// bytes = Wfp8[row = t*16 + (l&15)][col = kt*64 + k2*32 + ((l>>4)>>1)*16 + ((l>>4)&1)*8 ..+8].
// Logical row 200 = ones (rowsum trick), rows 201..207 = 0.
__global__ __launch_bounds__(256) void prep_w8(const float* __restrict__ W,
                                               unsigned long long* __restrict__ Wq) {
    const int i  = blockIdx.x * 256 + threadIdx.x;   // 12*13*64*2 = 19968 8-byte halves
    const int h  = i & 1;                            // k2
    const int j  = i >> 1;                           // (kt*13+t)*64 + l
    const int l  = j & 63;
    const int r2 = j >> 6;                           // kt*13 + t
    const int t  = r2 % 13;
    const int kt = r2 / 13;
    const int q  = l >> 4, m = l & 15;
    const int row = t * 16 + m;
    const int col = kt * 64 + h * 32 + ((q >> 1) << 4) + ((q & 1) << 3);
    unsigned long long v = 0ull;
    if (row < Csz) {
        const float4 a = *(const float4*)(W + (size_t)row * Dsz + col);
        const float4 b = *(const float4*)(W + (size_t)row * Dsz + col + 4);
        unsigned int lo = __builtin_amdgcn_cvt_pk_fp8_f32(a.x, a.y, 0u, false);
        lo = __builtin_amdgcn_cvt_pk_fp8_f32(a.z, a.w, lo, true);
        unsigned int hi = __builtin_amdgcn_cvt_pk_fp8_f32(b.x, b.y, 0u, false);
        hi = __builtin_amdgcn_cvt_pk_fp8_f32(b.z, b.w, hi, true);
        v = ((unsigned long long)hi << 32) | (unsigned long long)lo;
    } else if (row == Csz) {
        v = 0x3838383838383838ull;   // fp8 e4m3 1.0 x8
    }
    Wq[i] = v;
}

// global classifier runs FIRST: out[b,c] = ct[b]·gw[c] + gb[c]  (exact fp32)
__global__ __launch_bounds__(256) void gc_kernel(
    const float* __restrict__ ct, const float* __restrict__ gw,
    const float* __restrict__ gb, float* __restrict__ out) {
    const int b    = blockIdx.x;
    const int wv   = threadIdx.x >> 6;
    const int lane = threadIdx.x & 63;
    const int c    = blockIdx.y * 4 + wv;
    const float* wr = gw + (size_t)c * Dsz + lane * 12;
    const float* cr = ct + (size_t)b * Dsz + lane * 12;
    float s = 0.f;
#pragma unroll
    for (int j = 0; j < 3; ++j) {
        const float4 w = *(const float4*)(wr + 4 * j);
        const float4 x = *(const float4*)(cr + 4 * j);
        s += w.x * x.x + w.y * x.y + w.z * x.z + w.w * x.w;
    }
#pragma unroll
    for (int off = 32; off > 0; off >>= 1) s += __shfl_down(s, off, 64);
    if (lane == 0) out[b * Csz + c] = s + gb[c];
}

// Zero-LDS, zero-barrier: X direct global->VGPR (depth-2 pipeline), W read as
// pre-swizzled coalesced dwordx4 fragments straight from L1/L2.
// 192 threads (3 waves x 16 rows = MT 48), grid 768, 3 blocks/CU co-resident.
__global__ __launch_bounds__(192, 3) void attn_kernel(
    const float* __restrict__ X,            // (B*S, D) fp32
    const unsigned char* __restrict__ Wq,   // swizzled fragments, 156 KB
    const float* __restrict__ attn_b,       // (C,)
    const float* __restrict__ lam,          // (1,)
    float* __restrict__ out)                // (B, C): gscore already written
{
    const int tid  = threadIdx.x;
    const int lane = tid & 63;
    const int w    = tid >> 6;      // 0..2
    const int m    = lane & 15;
    const int q    = lane >> 4;
    const int rowbase = blockIdx.x * MT;
    const int bidx    = blockIdx.x / 12;          // 12 blocks per batch, never crosses

    // A-fragment source: lane (q,m) of wave w owns row w*16+m,
    // k-floats kt*64 + k2*32 + q*8 .. +8  (verified layout from prior rounds)
    const float* xp = X + (size_t)(rowbase + w * 16 + m) * Dsz + q * 8;
    // B-fragment source: per-lane 16 B within each 1024-B record
    const unsigned char* wp = Wq + lane * 16;

    // depth-2 X prefetch: slot kt&1, pieces j: (j>>1)=k2, (j&1)=lo/hi float4
    f32x4 xa[2][4];
#pragma unroll
    for (int kt = 0; kt < 2; ++kt) {
#pragma unroll
        for (int j = 0; j < 4; ++j)
            xa[kt][j] = *(const f32x4*)(xp + kt * 64 + (j >> 1) * 32 + (j & 1) * 4);
    }

    f32x4 acc[13];
#pragma unroll
    for (int t = 0; t < 13; ++t) acc[t] = (f32x4){0.f, 0.f, 0.f, 0.f};

#pragma unroll
    for (int kt = 0; kt < NKT; ++kt) {
        const int slot = kt & 1;
        // W fragments for this kt: 13 coalesced 16B/lane loads (1024 B/record)
        lx2 wf[13];
#pragma unroll
        for (int t = 0; t < 13; ++t)
            wf[t] = *(const lx2*)(wp + (size_t)(kt * 13 + t) * 1024);

        // refill consumed slot early (used at kt+2): loads fly under the MFMAs
        f32x4 xn[4];
        if (kt + 2 < NKT) {
#pragma unroll
            for (int j = 0; j < 4; ++j)
                xn[j] = *(const f32x4*)(xp + (kt + 2) * 64 + (j >> 1) * 32 + (j & 1) * 4);
        }

        // convert A fragments (both k2 halves) from slot
        union { long l; unsigned int u[2]; } A0, A1;
        {
            const f32x4 alo = xa[slot][0], ahi = xa[slot][1];
            A0.u[0] = __builtin_amdgcn_cvt_pk_fp8_f32(alo.x, alo.y, 0u, false);
            A0.u[0] = __builtin_amdgcn_cvt_pk_fp8_f32(alo.z, alo.w, A0.u[0], true);
            A0.u[1] = __builtin_amdgcn_cvt_pk_fp8_f32(ahi.x, ahi.y, 0u, false);
            A0.u[1] = __builtin_amdgcn_cvt_pk_fp8_f32(ahi.z, ahi.w, A0.u[1], true);
        }
        {
            const f32x4 alo = xa[slot][2], ahi = xa[slot][3];
            A1.u[0] = __builtin_amdgcn_cvt_pk_fp8_f32(alo.x, alo.y, 0u, false);
            A1.u[0] = __builtin_amdgcn_cvt_pk_fp8_f32(alo.z, alo.w, A1.u[0], true);
            A1.u[1] = __builtin_amdgcn_cvt_pk_fp8_f32(ahi.x, ahi.y, 0u, false);
            A1.u[1] = __builtin_amdgcn_cvt_pk_fp8_f32(ahi.z, ahi.w, A1.u[1], true);
        }

#pragma unroll
        for (int t = 0; t < 13; ++t)
            acc[t] = __builtin_amdgcn_mfma_f32_16x16x32_fp8_fp8(A0.l, wf[t][0], acc[t], 0, 0, 0);
#pragma unroll
        for (int t = 0; t < 13; ++t)
            acc[t] = __builtin_amdgcn_mfma_f32_16x16x32_fp8_fp8(A1.l, wf[t][1], acc[t], 0, 0, 0);

        if (kt + 2 < NKT) {
#pragma unroll
            for (int j = 0; j < 4; ++j) xa[slot][j] = xn[j];
        }
    }

    // rowsum via ones-column: tile 12, col 200 => m==8 lanes; row = q*4+r
    float rsv[4];
#pragma unroll
    for (int r = 0; r < 4; ++r) rsv[r] = __shfl(acc[12][r], (lane & 48) + 8, 64);

    const float scale = lam[0] * (1.f / ((float)Ssz * (float)Dsz));
    // epilogue: C/D col = lane&15, row = q*4+reg; reduce tile's 16 rows, atomic add
#pragma unroll
    for (int t = 0; t < 13; ++t) {
        const int c = t * 16 + m;
        if (c < Csz) {
            const float bias = attn_b[c];
            float s = 0.f;
#pragma unroll
            for (int r = 0; r < 4; ++r)
                s += rsv[r] / (1.f + __expf(-(acc[t][r] + bias)));
            s += __shfl_xor(s, 16, 64);
            s += __shfl_xor(s, 32, 64);
            if (q == 0) atomicAdd(&out[bidx * Csz + c], s * scale);
        }
    }
}

extern "C" void kernel_launch(void* const* d_in, const int* in_sizes, int n_in,
                              void* d_out, int out_size, void* d_ws, size_t ws_size,
                              hipStream_t stream) {
    const float* X   = (const float*)d_in[0];
    const float* ct  = (const float*)d_in[1];
    const float* aw  = (const float*)d_in[2];
    const float* ab  = (const float*)d_in[3];
    const float* gw  = (const float*)d_in[4];
    const float* gb  = (const float*)d_in[5];
    const float* lam = (const float*)d_in[6];
    float* out = (float*)d_out;
    unsigned long long* Wq = (unsigned long long*)d_ws;   // 12*13*1024 = 156 KB swizzled fp8

    prep_w8<<<(NKT * 13 * 64 * 2) / 256, 256, 0, stream>>>(aw, Wq);
    gc_kernel<<<dim3(Bsz, Csz / 4), 256, 0, stream>>>(ct, gw, gb, out);
    attn_kernel<<<(Bsz * Ssz) / MT, 192, 0, stream>>>(X, (const unsigned char*)Wq, ab, lam, out);
}